// Round 17
// baseline (289.582 us; speedup 1.0000x reference)
//
#include <hip/hip_runtime.h>

#define HID 64
#define NGRAPHS 64
#define LIN_NODES 64
#define EPB 8192        // edges per block in hist/scatter passes
#define BSH 9           // bucket shift: 512 nodes per bucket

// ---- bf16 helpers (RTNE pack, bit-shift unpack) ----
__device__ __forceinline__ unsigned rtne16(float f) {
  unsigned u = __float_as_uint(f);
  return (u + 0x7FFFu + ((u >> 16) & 1u)) >> 16;
}
__device__ __forceinline__ unsigned packbf(float a, float b) {
  return rtne16(a) | (rtne16(b) << 16);
}
__device__ __forceinline__ float blo(unsigned w) { return __uint_as_float(w << 16); }
__device__ __forceinline__ float bhi(unsigned w) { return __uint_as_float(w & 0xFFFF0000u); }

// ---------------- pass 1: per-(bucket,block) coarse histograms (LDS only) ------
__global__ __launch_bounds__(256) void k_hist(
    const int* __restrict__ src, const int* __restrict__ dst,
    int* __restrict__ countsD, int* __restrict__ countsS,
    int E, int NB, int KB) {
  __shared__ int hD[256], hS[256];
  int t = threadIdx.x;
  hD[t] = 0; hS[t] = 0;
  __syncthreads();
  int e0 = blockIdx.x * EPB;
  for (int i = 0; i < EPB / 256; ++i) {
    int e = e0 + i * 256 + t;
    if (e < E) {
      atomicAdd(&hD[dst[e] >> BSH], 1);
      atomicAdd(&hS[src[e] >> BSH], 1);
    }
  }
  __syncthreads();
  if (t < NB) {
    countsD[t * KB + blockIdx.x] = hD[t];
    countsS[t * KB + blockIdx.x] = hS[t];
  }
}

// ---------------- pass 2a: per-row exclusive scan (one block per bucket row) ---
__global__ __launch_bounds__(256) void k_scanA(
    int* __restrict__ A0, int* __restrict__ A1, int* __restrict__ rows,
    int NB, int KB) {
  int bid = blockIdx.x;
  int* A = (bid < NB) ? A0 : A1;
  int row = (bid < NB) ? bid : bid - NB;
  __shared__ int s[256];
  int t = threadIdx.x;
  int base = row * KB + t * 4;
  int v0 = (t * 4 + 0 < KB) ? A[base + 0] : 0;
  int v1 = (t * 4 + 1 < KB) ? A[base + 1] : 0;
  int v2 = (t * 4 + 2 < KB) ? A[base + 2] : 0;
  int v3 = (t * 4 + 3 < KB) ? A[base + 3] : 0;
  int sum = v0 + v1 + v2 + v3;
  s[t] = sum;
  __syncthreads();
  for (int o = 1; o < 256; o <<= 1) {
    int x = (t >= o) ? s[t - o] : 0;
    __syncthreads();
    s[t] += x;
    __syncthreads();
  }
  int excl = s[t] - sum;
  if (t * 4 + 0 < KB) A[base + 0] = excl;
  if (t * 4 + 1 < KB) A[base + 1] = excl + v0;
  if (t * 4 + 2 < KB) A[base + 2] = excl + v0 + v1;
  if (t * 4 + 3 < KB) A[base + 3] = excl + v0 + v1 + v2;
  if (t == 255) rows[bid] = s[255];
}

// ---------------- pass 2b: exclusive scan of row totals (2 arrays) -------------
__global__ __launch_bounds__(256) void k_scanB(int* __restrict__ rows, int NB) {
  __shared__ int s[256];
  int t = threadIdx.x;
  int* R = rows + blockIdx.x * NB;
  int v = (t < NB) ? R[t] : 0;
  s[t] = v;
  __syncthreads();
  for (int o = 1; o < 256; o <<= 1) {
    int x = (t >= o) ? s[t - o] : 0;
    __syncthreads();
    s[t] += x;
    __syncthreads();
  }
  if (t < NB) R[t] = s[t] - v;
}

// ---------------- pass 3: scatter edges into bucket-grouped buffers ------------
__global__ __launch_bounds__(256) void k_scat(
    const int* __restrict__ src, const int* __restrict__ dst,
    const int* __restrict__ exclD, const int* __restrict__ exclS,
    const int* __restrict__ rows,
    unsigned* __restrict__ bufD, unsigned short* __restrict__ bufS,
    int E, int NB, int KB) {
  __shared__ int cD[256], cS[256];
  int t = threadIdx.x;
  if (t < NB) {
    cD[t] = exclD[t * KB + blockIdx.x] + rows[t];
    cS[t] = exclS[t * KB + blockIdx.x] + rows[NB + t];
  }
  __syncthreads();
  int e0 = blockIdx.x * EPB;
  for (int i = 0; i < EPB / 256; ++i) {
    int e = e0 + i * 256 + t;
    if (e < E) {
      int s = src[e], d = dst[e];
      int pd = atomicAdd(&cD[d >> BSH], 1);
      bufD[pd] = (unsigned)s | ((unsigned)(d & 511) << 17);
      int ps = atomicAdd(&cS[s >> BSH], 1);
      bufS[ps] = (unsigned short)(s & 511);
    }
  }
}

// ---------------- pass 4: per-bucket fine histogram -> deg/offs/norm/csr -------
__global__ __launch_bounds__(256) void k_csrB(
    const unsigned* __restrict__ bufD, const unsigned short* __restrict__ bufS,
    const int* __restrict__ exclD, const int* __restrict__ exclS,
    const int* __restrict__ rows,
    int* __restrict__ csr, int* __restrict__ deg, int* __restrict__ offs,
    float* __restrict__ nI, float* __restrict__ nO,
    int E, int N, int NB, int KB) {
  __shared__ int hist[512], loc[512];
  int t = threadIdx.x;
  hist[t] = 0; hist[t + 256] = 0;
  __syncthreads();
  int bid = blockIdx.x;
  if (bid < NB) {
    int beg = exclD[bid * KB] + rows[bid];
    int end = (bid + 1 < NB) ? exclD[(bid + 1) * KB] + rows[bid + 1] : E;
    for (int i = beg + t; i < end; i += 256)
      atomicAdd(&hist[(bufD[i] >> 17) & 511], 1);
    __syncthreads();
    if (t == 0) {
      int run = 0;
      for (int i = 0; i < 512; ++i) { loc[i] = run; run += hist[i]; }
    }
    __syncthreads();
#pragma unroll
    for (int k = 0; k < 2; ++k) {
      int bin = t + k * 256;
      int n = (bid << BSH) + bin;
      if (n < N) {
        int dgv = hist[bin];
        deg[n] = dgv;
        offs[n] = beg + loc[bin];
        nI[n] = rsqrtf((float)(dgv > 1 ? dgv : 1));
      }
    }
    __syncthreads();
    for (int i = beg + t; i < end; i += 256) {
      unsigned w = bufD[i];
      int r = atomicAdd(&loc[(w >> 17) & 511], 1);
      csr[beg + r] = (int)(w & 0x1FFFFu);
    }
  } else {
    int b = bid - NB;
    int beg = exclS[b * KB] + rows[NB + b];
    int end = (b + 1 < NB) ? exclS[(b + 1) * KB] + rows[NB + b + 1] : E;
    for (int i = beg + t; i < end; i += 256)
      atomicAdd(&hist[bufS[i]], 1);
    __syncthreads();
#pragma unroll
    for (int k = 0; k < 2; ++k) {
      int bin = t + k * 256;
      int n = (b << BSH) + bin;
      if (n < N) {
        int dgv = hist[bin];
        nO[n] = rsqrtf((float)(dgv > 1 ? dgv : 1));
      }
    }
  }
}

// ---------------- fused sort + embed + count (independent jobs, one dispatch) --
// blocks [0, nbS): per-node register bitonic-32 src-sort of csr segments
// blocks [nbS, nbS+nbE): embedding gather pre-scaled by nO, bf16 out
// blocks [nbS+nbE, ...): per-graph node counts via LDS histogram
__global__ __launch_bounds__(256) void k_fused(
    int* __restrict__ csr, const int* __restrict__ offs,
    const int* __restrict__ deg,
    const int* __restrict__ feat, const float* __restrict__ emb,
    const float* __restrict__ nO, unsigned short* __restrict__ h,
    const int* __restrict__ gid, int* __restrict__ cnt, int N,
    int nbS, int nbE) {
  __shared__ int hh[NGRAPHS];
  int bid = blockIdx.x;
  if (bid < nbS) {
    int n = bid * 256 + threadIdx.x;
    if (n >= N) return;
    int d = deg[n];
    if (d < 2 || d > 32) return;
    int r0 = offs[n];
    int v[32];
#pragma unroll
    for (int i = 0; i < 32; ++i) v[i] = (i < d) ? csr[r0 + i] : 0x7FFFFFFF;
#pragma unroll
    for (int k = 2; k <= 32; k <<= 1) {
#pragma unroll
      for (int j = k >> 1; j > 0; j >>= 1) {
#pragma unroll
        for (int i = 0; i < 32; ++i) {
          int l = i ^ j;
          if (l > i) {
            bool up = ((i & k) == 0);
            int a = v[i], c = v[l];
            if ((a > c) == up) { v[i] = c; v[l] = a; }
          }
        }
      }
    }
#pragma unroll
    for (int i = 0; i < 32; ++i)
      if (i < d) csr[r0 + i] = v[i];
  } else if (bid < nbS + nbE) {
    int t = (bid - nbS) * 256 + threadIdx.x;
    int n = t >> 4, q = t & 15;
    if (n >= N) return;
    float4 v = *(const float4*)(emb + (size_t)feat[n] * HID + q * 4);
    float s = nO[n];
    uint2 o;
    o.x = packbf(v.x * s, v.y * s);
    o.y = packbf(v.z * s, v.w * s);
    *(uint2*)(h + (size_t)n * HID + q * 4) = o;
  } else {
    int t = threadIdx.x;
    if (t < NGRAPHS) hh[t] = 0;
    __syncthreads();
    int n = (bid - nbS - nbE) * 256 + t;
    if (n < N) atomicAdd(&hh[gid[n]], 1);
    __syncthreads();
    if (t < NGRAPHS && hh[t]) atomicAdd(&cnt[t], hh[t]);
  }
}

// ---------------- fused gather + linear (+ pool epilogue on last layer) --------
// h is fully L3-resident (12.8 MB): L2 misses are ~300-500cy L3 hits, so the
// gather is latency*concurrency-bound. launch_bounds(256,8) -> 32 waves/CU
// (R15 measured 39% occupancy at (256,4); VGPR=40 and 16KB LDS permit 8 blocks).
template <bool LAST>
__global__ __launch_bounds__(256, 8) void k_gl(
    const unsigned short* __restrict__ hs, const int* __restrict__ csr,
    const int* __restrict__ offs, const int* __restrict__ deg,
    const float* __restrict__ nI, const float* __restrict__ W,
    const float* __restrict__ b, unsigned short* __restrict__ outb,
    const int* __restrict__ gid, float* __restrict__ sums,
    int N, const float* __restrict__ postscale) {
  __shared__ float xs[LIN_NODES * HID];  // 16 KB (only LDS use)
  int t = threadIdx.x;

  int n0 = blockIdx.x * LIN_NODES;
  int gnode = t >> 2, q = t & 3;         // 64 nodes x 4 lanes
  int n = n0 + gnode;
  float4 a0 = make_float4(0.f, 0.f, 0.f, 0.f), a1 = a0, a2 = a0, a3 = a0;
  if (n < N) {
    int r0 = offs[n];
    int d = deg[n];
    int i = 0;
    for (; i + 1 < d; i += 2) {
      int s0 = csr[r0 + i], s1 = csr[r0 + i + 1];
      const uint4* p0 = (const uint4*)(hs + (size_t)s0 * HID) + q * 2;
      const uint4* p1 = (const uint4*)(hs + (size_t)s1 * HID) + q * 2;
      uint4 u0 = p0[0], u1 = p0[1];
      uint4 w0 = p1[0], w1 = p1[1];
      a0.x += blo(u0.x) + blo(w0.x); a0.y += bhi(u0.x) + bhi(w0.x);
      a0.z += blo(u0.y) + blo(w0.y); a0.w += bhi(u0.y) + bhi(w0.y);
      a1.x += blo(u0.z) + blo(w0.z); a1.y += bhi(u0.z) + bhi(w0.z);
      a1.z += blo(u0.w) + blo(w0.w); a1.w += bhi(u0.w) + bhi(w0.w);
      a2.x += blo(u1.x) + blo(w1.x); a2.y += bhi(u1.x) + bhi(w1.x);
      a2.z += blo(u1.y) + blo(w1.y); a2.w += bhi(u1.y) + bhi(w1.y);
      a3.x += blo(u1.z) + blo(w1.z); a3.y += bhi(u1.z) + bhi(w1.z);
      a3.z += blo(u1.w) + blo(w1.w); a3.w += bhi(u1.w) + bhi(w1.w);
    }
    if (i < d) {
      int s0 = csr[r0 + i];
      const uint4* p0 = (const uint4*)(hs + (size_t)s0 * HID) + q * 2;
      uint4 u0 = p0[0], u1 = p0[1];
      a0.x += blo(u0.x); a0.y += bhi(u0.x); a0.z += blo(u0.y); a0.w += bhi(u0.y);
      a1.x += blo(u0.z); a1.y += bhi(u0.z); a1.z += blo(u0.w); a1.w += bhi(u0.w);
      a2.x += blo(u1.x); a2.y += bhi(u1.x); a2.z += blo(u1.y); a2.w += bhi(u1.y);
      a3.x += blo(u1.z); a3.y += bhi(u1.z); a3.z += blo(u1.w); a3.w += bhi(u1.w);
    }
    float sc = nI[n];
    a0.x *= sc; a0.y *= sc; a0.z *= sc; a0.w *= sc;
    a1.x *= sc; a1.y *= sc; a1.z *= sc; a1.w *= sc;
    a2.x *= sc; a2.y *= sc; a2.z *= sc; a2.w *= sc;
    a3.x *= sc; a3.y *= sc; a3.z *= sc; a3.w *= sc;
  }
  float* xp = xs + gnode * HID + q * 16;
  *(float4*)(xp) = a0;
  *(float4*)(xp + 4) = a1;
  *(float4*)(xp + 8) = a2;
  *(float4*)(xp + 12) = a3;
  __syncthreads();

  int j = t & 63, rg = t >> 6;  // 4 waves x 16 nodes; lane j = output col
  float4 wc[16];
#pragma unroll
  for (int k4 = 0; k4 < 16; ++k4)
    wc[k4] = make_float4(W[(4 * k4 + 0) * HID + j], W[(4 * k4 + 1) * HID + j],
                         W[(4 * k4 + 2) * HID + j], W[(4 * k4 + 3) * HID + j]);
  float bj = b[j];
  for (int r = 0; r < LIN_NODES / 4; ++r) {
    int node = rg * (LIN_NODES / 4) + r;
    float acc = bj;
    const float* xr = xs + node * HID;
#pragma unroll
    for (int k4 = 0; k4 < 16; ++k4) {
      float4 x4 = *(const float4*)(xr + k4 * 4);
      acc = fmaf(x4.x, wc[k4].x, acc);
      acc = fmaf(x4.y, wc[k4].y, acc);
      acc = fmaf(x4.z, wc[k4].z, acc);
      acc = fmaf(x4.w, wc[k4].w, acc);
    }
    int nn = n0 + node;
    if (LAST) {
      if (nn < N) xs[node * HID + j] = fmaxf(acc, 0.f);
    } else {
      float val = fmaxf(acc, 0.f) * postscale[nn < N ? nn : 0];
      float other = __shfl_xor(val, 1);
      if (nn < N && (j & 1) == 0)
        *(unsigned*)(outb + (size_t)nn * HID + j) = packbf(val, other);
    }
  }
  if (LAST) {
    __syncthreads();
    if (t < 64) {  // one wave run-length-pools 64 sorted-gid nodes from LDS
      int cur = -1;
      float acc = 0.f;
      for (int i = 0; i < LIN_NODES; ++i) {
        int nn = n0 + i;
        if (nn >= N) break;
        int g = gid[nn];
        float v = xs[i * HID + t];
        if (g != cur) {
          if (cur >= 0) unsafeAtomicAdd(&sums[cur * HID + t], acc);
          cur = g; acc = v;
        } else {
          acc += v;
        }
      }
      if (cur >= 0) unsafeAtomicAdd(&sums[cur * HID + t], acc);
    }
  }
}

// ---------------- mean ----------------
__global__ void k_div(const float* __restrict__ sums, const int* __restrict__ cnt,
                      float* __restrict__ out) {
  int i = blockIdx.x * 256 + threadIdx.x;
  if (i >= NGRAPHS * HID) return;
  float c = (float)cnt[i >> 6];
  out[i] = sums[i] / fmaxf(c, 1.f);
}

extern "C" void kernel_launch(void* const* d_in, const int* in_sizes, int n_in,
                              void* d_out, int out_size, void* d_ws, size_t ws_size,
                              hipStream_t stream) {
  const int* node_feat = (const int*)d_in[0];
  const int* src = (const int*)d_in[1];
  const int* dst = (const int*)d_in[2];
  const int* gid = (const int*)d_in[3];
  const float* emb = (const float*)d_in[4];
  const float* W[3] = {(const float*)d_in[5], (const float*)d_in[7], (const float*)d_in[9]};
  const float* b[3] = {(const float*)d_in[6], (const float*)d_in[8], (const float*)d_in[10]};
  float* out = (float*)d_out;
  int N = in_sizes[0];
  int E = in_sizes[1];
  int NB = (N + 511) >> BSH;          // 196 coarse buckets (512 nodes each)
  int KB = (E + EPB - 1) / EPB;       // 196 edge blocks
  int MD = NB * KB;

  char* ws = (char*)d_ws;
  size_t off_b = 0;
  auto alloc = [&](size_t bytes) {
    char* p = ws + off_b;
    off_b = (off_b + bytes + 255) & ~(size_t)255;
    return p;
  };
  // Zero-init buffers first; ONE memset covers the whole span.
  float* sums = (float*)alloc(NGRAPHS * HID * 4);
  int* cnt = (int*)alloc(NGRAPHS * 4);
  size_t zero_span = off_b;
  int* countsD = (int*)alloc((size_t)MD * 4);
  int* countsS = (int*)alloc((size_t)MD * 4);
  int* rows = (int*)alloc((size_t)2 * NB * 4);   // row totals -> row bases
  unsigned* bufD = (unsigned*)alloc((size_t)E * 4);
  unsigned short* bufS = (unsigned short*)alloc((size_t)E * 2);
  int* csr = (int*)alloc((size_t)E * 4);
  int* deg = (int*)alloc((size_t)N * 4);
  int* offs = (int*)alloc((size_t)N * 4);
  float* nI = (float*)alloc((size_t)N * 4);
  float* nO = (float*)alloc((size_t)N * 4);
  unsigned short* hb0 = (unsigned short*)alloc((size_t)N * HID * 2);  // bf16 h
  unsigned short* hb1 = (unsigned short*)alloc((size_t)N * HID * 2);  // bf16 h

  hipMemsetAsync(ws, 0, zero_span, stream);

  // counting-sort CSR build: zero global atomics (LDS atomics only)
  k_hist<<<KB, 256, 0, stream>>>(src, dst, countsD, countsS, E, NB, KB);
  k_scanA<<<2 * NB, 256, 0, stream>>>(countsD, countsS, rows, NB, KB);
  k_scanB<<<2, 256, 0, stream>>>(rows, NB);
  k_scat<<<KB, 256, 0, stream>>>(src, dst, countsD, countsS, rows, bufD, bufS, E, NB, KB);
  k_csrB<<<2 * NB, 256, 0, stream>>>(bufD, bufS, countsD, countsS, rows, csr, deg,
                                     offs, nI, nO, E, N, NB, KB);

  // sort + embed + per-graph count in one dispatch
  int nblk = (N + 255) / 256;
  int nbS = nblk;
  int nbE = N / 16 + 1;
  k_fused<<<nbS + nbE + nblk, 256, 0, stream>>>(
      csr, offs, deg, node_feat, emb, nO, hb0, gid, cnt, N, nbS, nbE);

  int nblkG = (N + LIN_NODES - 1) / LIN_NODES;
  k_gl<false><<<nblkG, 256, 0, stream>>>(hb0, csr, offs, deg, nI, W[0], b[0],
                                         hb1, nullptr, nullptr, N, nO);
  k_gl<false><<<nblkG, 256, 0, stream>>>(hb1, csr, offs, deg, nI, W[1], b[1],
                                         hb0, nullptr, nullptr, N, nO);
  k_gl<true><<<nblkG, 256, 0, stream>>>(hb0, csr, offs, deg, nI, W[2], b[2],
                                        nullptr, gid, sums, N, nullptr);

  k_div<<<(NGRAPHS * HID + 255) / 256, 256, 0, stream>>>(sums, cnt, out);
}

// Round 18
// 253.965 us; speedup vs baseline: 1.1402x; 1.1402x over previous
//
#include <hip/hip_runtime.h>

#define HID 64
#define NGRAPHS 64
#define LIN_NODES 32
#define EPB 8192        // edges per block in hist/scatter passes
#define BSH 9           // bucket shift: 512 nodes per bucket

// ---- bf16 helpers (RTNE pack, bit-shift unpack) ----
__device__ __forceinline__ unsigned rtne16(float f) {
  unsigned u = __float_as_uint(f);
  return (u + 0x7FFFu + ((u >> 16) & 1u)) >> 16;
}
__device__ __forceinline__ unsigned packbf(float a, float b) {
  return rtne16(a) | (rtne16(b) << 16);
}
__device__ __forceinline__ float blo(unsigned w) { return __uint_as_float(w << 16); }
__device__ __forceinline__ float bhi(unsigned w) { return __uint_as_float(w & 0xFFFF0000u); }

// ---------------- pass 1: per-(bucket,block) coarse histograms (LDS only) ------
__global__ __launch_bounds__(256) void k_hist(
    const int* __restrict__ src, const int* __restrict__ dst,
    int* __restrict__ countsD, int* __restrict__ countsS,
    int E, int NB, int KB) {
  __shared__ int hD[256], hS[256];
  int t = threadIdx.x;
  hD[t] = 0; hS[t] = 0;
  __syncthreads();
  int e0 = blockIdx.x * EPB;
  for (int i = 0; i < EPB / 256; ++i) {
    int e = e0 + i * 256 + t;
    if (e < E) {
      atomicAdd(&hD[dst[e] >> BSH], 1);
      atomicAdd(&hS[src[e] >> BSH], 1);
    }
  }
  __syncthreads();
  if (t < NB) {
    countsD[t * KB + blockIdx.x] = hD[t];
    countsS[t * KB + blockIdx.x] = hS[t];
  }
}

// ---------------- pass 2a: per-row exclusive scan (one block per bucket row) ---
__global__ __launch_bounds__(256) void k_scanA(
    int* __restrict__ A0, int* __restrict__ A1, int* __restrict__ rows,
    int NB, int KB) {
  int bid = blockIdx.x;
  int* A = (bid < NB) ? A0 : A1;
  int row = (bid < NB) ? bid : bid - NB;
  __shared__ int s[256];
  int t = threadIdx.x;
  int base = row * KB + t * 4;
  int v0 = (t * 4 + 0 < KB) ? A[base + 0] : 0;
  int v1 = (t * 4 + 1 < KB) ? A[base + 1] : 0;
  int v2 = (t * 4 + 2 < KB) ? A[base + 2] : 0;
  int v3 = (t * 4 + 3 < KB) ? A[base + 3] : 0;
  int sum = v0 + v1 + v2 + v3;
  s[t] = sum;
  __syncthreads();
  for (int o = 1; o < 256; o <<= 1) {
    int x = (t >= o) ? s[t - o] : 0;
    __syncthreads();
    s[t] += x;
    __syncthreads();
  }
  int excl = s[t] - sum;
  if (t * 4 + 0 < KB) A[base + 0] = excl;
  if (t * 4 + 1 < KB) A[base + 1] = excl + v0;
  if (t * 4 + 2 < KB) A[base + 2] = excl + v0 + v1;
  if (t * 4 + 3 < KB) A[base + 3] = excl + v0 + v1 + v2;
  if (t == 255) rows[bid] = s[255];
}

// ---------------- pass 2b: exclusive scan of row totals (2 arrays) -------------
__global__ __launch_bounds__(256) void k_scanB(int* __restrict__ rows, int NB) {
  __shared__ int s[256];
  int t = threadIdx.x;
  int* R = rows + blockIdx.x * NB;
  int v = (t < NB) ? R[t] : 0;
  s[t] = v;
  __syncthreads();
  for (int o = 1; o < 256; o <<= 1) {
    int x = (t >= o) ? s[t - o] : 0;
    __syncthreads();
    s[t] += x;
    __syncthreads();
  }
  if (t < NB) R[t] = s[t] - v;
}

// ---------------- pass 3: scatter edges into bucket-grouped buffers ------------
__global__ __launch_bounds__(256) void k_scat(
    const int* __restrict__ src, const int* __restrict__ dst,
    const int* __restrict__ exclD, const int* __restrict__ exclS,
    const int* __restrict__ rows,
    unsigned* __restrict__ bufD, unsigned short* __restrict__ bufS,
    int E, int NB, int KB) {
  __shared__ int cD[256], cS[256];
  int t = threadIdx.x;
  if (t < NB) {
    cD[t] = exclD[t * KB + blockIdx.x] + rows[t];
    cS[t] = exclS[t * KB + blockIdx.x] + rows[NB + t];
  }
  __syncthreads();
  int e0 = blockIdx.x * EPB;
  for (int i = 0; i < EPB / 256; ++i) {
    int e = e0 + i * 256 + t;
    if (e < E) {
      int s = src[e], d = dst[e];
      int pd = atomicAdd(&cD[d >> BSH], 1);
      bufD[pd] = (unsigned)s | ((unsigned)(d & 511) << 17);
      int ps = atomicAdd(&cS[s >> BSH], 1);
      bufS[ps] = (unsigned short)(s & 511);
    }
  }
}

// ---------------- pass 4: per-bucket fine histogram -> deg/offs/norm/csr -------
__global__ __launch_bounds__(256) void k_csrB(
    const unsigned* __restrict__ bufD, const unsigned short* __restrict__ bufS,
    const int* __restrict__ exclD, const int* __restrict__ exclS,
    const int* __restrict__ rows,
    int* __restrict__ csr, int* __restrict__ deg, int* __restrict__ offs,
    float* __restrict__ nI, float* __restrict__ nO,
    int E, int N, int NB, int KB) {
  __shared__ int hist[512], loc[512];
  int t = threadIdx.x;
  hist[t] = 0; hist[t + 256] = 0;
  __syncthreads();
  int bid = blockIdx.x;
  if (bid < NB) {
    int beg = exclD[bid * KB] + rows[bid];
    int end = (bid + 1 < NB) ? exclD[(bid + 1) * KB] + rows[bid + 1] : E;
    for (int i = beg + t; i < end; i += 256)
      atomicAdd(&hist[(bufD[i] >> 17) & 511], 1);
    __syncthreads();
    if (t == 0) {
      int run = 0;
      for (int i = 0; i < 512; ++i) { loc[i] = run; run += hist[i]; }
    }
    __syncthreads();
#pragma unroll
    for (int k = 0; k < 2; ++k) {
      int bin = t + k * 256;
      int n = (bid << BSH) + bin;
      if (n < N) {
        int dgv = hist[bin];
        deg[n] = dgv;
        offs[n] = beg + loc[bin];
        nI[n] = rsqrtf((float)(dgv > 1 ? dgv : 1));
      }
    }
    __syncthreads();
    for (int i = beg + t; i < end; i += 256) {
      unsigned w = bufD[i];
      int r = atomicAdd(&loc[(w >> 17) & 511], 1);
      csr[beg + r] = (int)(w & 0x1FFFFu);
    }
  } else {
    int b = bid - NB;
    int beg = exclS[b * KB] + rows[NB + b];
    int end = (b + 1 < NB) ? exclS[(b + 1) * KB] + rows[NB + b + 1] : E;
    for (int i = beg + t; i < end; i += 256)
      atomicAdd(&hist[bufS[i]], 1);
    __syncthreads();
#pragma unroll
    for (int k = 0; k < 2; ++k) {
      int bin = t + k * 256;
      int n = (b << BSH) + bin;
      if (n < N) {
        int dgv = hist[bin];
        nO[n] = rsqrtf((float)(dgv > 1 ? dgv : 1));
      }
    }
  }
}

// ---------------- fused sort + embed + count (independent jobs, one dispatch) --
__global__ __launch_bounds__(256) void k_fused(
    int* __restrict__ csr, const int* __restrict__ offs,
    const int* __restrict__ deg,
    const int* __restrict__ feat, const float* __restrict__ emb,
    const float* __restrict__ nO, unsigned short* __restrict__ h,
    const int* __restrict__ gid, int* __restrict__ cnt, int N,
    int nbS, int nbE) {
  __shared__ int hh[NGRAPHS];
  int bid = blockIdx.x;
  if (bid < nbS) {
    int n = bid * 256 + threadIdx.x;
    if (n >= N) return;
    int d = deg[n];
    if (d < 2 || d > 32) return;
    int r0 = offs[n];
    int v[32];
#pragma unroll
    for (int i = 0; i < 32; ++i) v[i] = (i < d) ? csr[r0 + i] : 0x7FFFFFFF;
#pragma unroll
    for (int k = 2; k <= 32; k <<= 1) {
#pragma unroll
      for (int j = k >> 1; j > 0; j >>= 1) {
#pragma unroll
        for (int i = 0; i < 32; ++i) {
          int l = i ^ j;
          if (l > i) {
            bool up = ((i & k) == 0);
            int a = v[i], c = v[l];
            if ((a > c) == up) { v[i] = c; v[l] = a; }
          }
        }
      }
    }
#pragma unroll
    for (int i = 0; i < 32; ++i)
      if (i < d) csr[r0 + i] = v[i];
  } else if (bid < nbS + nbE) {
    int t = (bid - nbS) * 256 + threadIdx.x;
    int n = t >> 4, q = t & 15;
    if (n >= N) return;
    float4 v = *(const float4*)(emb + (size_t)feat[n] * HID + q * 4);
    float s = nO[n];
    uint2 o;
    o.x = packbf(v.x * s, v.y * s);
    o.y = packbf(v.z * s, v.w * s);
    *(uint2*)(h + (size_t)n * HID + q * 4) = o;
  } else {
    int t = threadIdx.x;
    if (t < NGRAPHS) hh[t] = 0;
    __syncthreads();
    int n = (bid - nbS - nbE) * 256 + t;
    if (n < N) atomicAdd(&hh[gid[n]], 1);
    __syncthreads();
    if (t < NGRAPHS && hh[t]) atomicAdd(&cnt[t], hh[t]);
  }
}

// ---------------- fused gather + linear (+ pool epilogue on last layer) --------
// R16 lesson: (256,8) forced VGPR 40->32 and killed per-wave MLP (57.4->71us).
// Occupancy at (256,4) was grid-limited (1563 blocks = 6.1/CU), not resource-
// limited. Fix: 32 nodes/block, 8 lanes/node (1 uint4 each) -> 3125 blocks
// = 12.2/CU, 8 KB LDS, small reg footprint; (256,4) keeps the allocator loose.
template <bool LAST>
__global__ __launch_bounds__(256, 4) void k_gl(
    const unsigned short* __restrict__ hs, const int* __restrict__ csr,
    const int* __restrict__ offs, const int* __restrict__ deg,
    const float* __restrict__ nI, const float* __restrict__ W,
    const float* __restrict__ b, unsigned short* __restrict__ outb,
    const int* __restrict__ gid, float* __restrict__ sums,
    int N, const float* __restrict__ postscale) {
  __shared__ float xs[LIN_NODES * HID];  // 8 KB (only LDS use)
  int t = threadIdx.x;

  int n0 = blockIdx.x * LIN_NODES;
  int gnode = t >> 3, q = t & 7;         // 32 nodes x 8 lanes; lane q = cols q*8..+7
  int n = n0 + gnode;
  float4 a0 = make_float4(0.f, 0.f, 0.f, 0.f), a1 = a0;
  if (n < N) {
    int r0 = offs[n];
    int d = deg[n];
    int i = 0;
    for (; i + 1 < d; i += 2) {
      int s0 = csr[r0 + i], s1 = csr[r0 + i + 1];
      uint4 u0 = *((const uint4*)(hs + (size_t)s0 * HID) + q);
      uint4 w0 = *((const uint4*)(hs + (size_t)s1 * HID) + q);
      a0.x += blo(u0.x) + blo(w0.x); a0.y += bhi(u0.x) + bhi(w0.x);
      a0.z += blo(u0.y) + blo(w0.y); a0.w += bhi(u0.y) + bhi(w0.y);
      a1.x += blo(u0.z) + blo(w0.z); a1.y += bhi(u0.z) + bhi(w0.z);
      a1.z += blo(u0.w) + blo(w0.w); a1.w += bhi(u0.w) + bhi(w0.w);
    }
    if (i < d) {
      int s0 = csr[r0 + i];
      uint4 u0 = *((const uint4*)(hs + (size_t)s0 * HID) + q);
      a0.x += blo(u0.x); a0.y += bhi(u0.x); a0.z += blo(u0.y); a0.w += bhi(u0.y);
      a1.x += blo(u0.z); a1.y += bhi(u0.z); a1.z += blo(u0.w); a1.w += bhi(u0.w);
    }
    float sc = nI[n];
    a0.x *= sc; a0.y *= sc; a0.z *= sc; a0.w *= sc;
    a1.x *= sc; a1.y *= sc; a1.z *= sc; a1.w *= sc;
  }
  float* xp = xs + gnode * HID + q * 8;
  *(float4*)(xp) = a0;
  *(float4*)(xp + 4) = a1;
  __syncthreads();

  int j = t & 63, rg = t >> 6;  // 4 waves x 8 nodes; lane j = output col
  float4 wc[16];
#pragma unroll
  for (int k4 = 0; k4 < 16; ++k4)
    wc[k4] = make_float4(W[(4 * k4 + 0) * HID + j], W[(4 * k4 + 1) * HID + j],
                         W[(4 * k4 + 2) * HID + j], W[(4 * k4 + 3) * HID + j]);
  float bj = b[j];
  for (int r = 0; r < LIN_NODES / 4; ++r) {
    int node = rg * (LIN_NODES / 4) + r;
    float acc = bj;
    const float* xr = xs + node * HID;
#pragma unroll
    for (int k4 = 0; k4 < 16; ++k4) {
      float4 x4 = *(const float4*)(xr + k4 * 4);
      acc = fmaf(x4.x, wc[k4].x, acc);
      acc = fmaf(x4.y, wc[k4].y, acc);
      acc = fmaf(x4.z, wc[k4].z, acc);
      acc = fmaf(x4.w, wc[k4].w, acc);
    }
    int nn = n0 + node;
    if (LAST) {
      if (nn < N) xs[node * HID + j] = fmaxf(acc, 0.f);
    } else {
      float val = fmaxf(acc, 0.f) * postscale[nn < N ? nn : 0];
      float other = __shfl_xor(val, 1);
      if (nn < N && (j & 1) == 0)
        *(unsigned*)(outb + (size_t)nn * HID + j) = packbf(val, other);
    }
  }
  if (LAST) {
    __syncthreads();
    if (t < 64) {  // one wave run-length-pools the block's sorted-gid nodes
      int cur = -1;
      float acc = 0.f;
      for (int i = 0; i < LIN_NODES; ++i) {
        int nn = n0 + i;
        if (nn >= N) break;
        int g = gid[nn];
        float v = xs[i * HID + t];
        if (g != cur) {
          if (cur >= 0) unsafeAtomicAdd(&sums[cur * HID + t], acc);
          cur = g; acc = v;
        } else {
          acc += v;
        }
      }
      if (cur >= 0) unsafeAtomicAdd(&sums[cur * HID + t], acc);
    }
  }
}

// ---------------- mean ----------------
__global__ void k_div(const float* __restrict__ sums, const int* __restrict__ cnt,
                      float* __restrict__ out) {
  int i = blockIdx.x * 256 + threadIdx.x;
  if (i >= NGRAPHS * HID) return;
  float c = (float)cnt[i >> 6];
  out[i] = sums[i] / fmaxf(c, 1.f);
}

extern "C" void kernel_launch(void* const* d_in, const int* in_sizes, int n_in,
                              void* d_out, int out_size, void* d_ws, size_t ws_size,
                              hipStream_t stream) {
  const int* node_feat = (const int*)d_in[0];
  const int* src = (const int*)d_in[1];
  const int* dst = (const int*)d_in[2];
  const int* gid = (const int*)d_in[3];
  const float* emb = (const float*)d_in[4];
  const float* W[3] = {(const float*)d_in[5], (const float*)d_in[7], (const float*)d_in[9]};
  const float* b[3] = {(const float*)d_in[6], (const float*)d_in[8], (const float*)d_in[10]};
  float* out = (float*)d_out;
  int N = in_sizes[0];
  int E = in_sizes[1];
  int NB = (N + 511) >> BSH;          // 196 coarse buckets (512 nodes each)
  int KB = (E + EPB - 1) / EPB;       // 196 edge blocks
  int MD = NB * KB;

  char* ws = (char*)d_ws;
  size_t off_b = 0;
  auto alloc = [&](size_t bytes) {
    char* p = ws + off_b;
    off_b = (off_b + bytes + 255) & ~(size_t)255;
    return p;
  };
  // Zero-init buffers first; ONE memset covers the whole span.
  float* sums = (float*)alloc(NGRAPHS * HID * 4);
  int* cnt = (int*)alloc(NGRAPHS * 4);
  size_t zero_span = off_b;
  int* countsD = (int*)alloc((size_t)MD * 4);
  int* countsS = (int*)alloc((size_t)MD * 4);
  int* rows = (int*)alloc((size_t)2 * NB * 4);   // row totals -> row bases
  unsigned* bufD = (unsigned*)alloc((size_t)E * 4);
  unsigned short* bufS = (unsigned short*)alloc((size_t)E * 2);
  int* csr = (int*)alloc((size_t)E * 4);
  int* deg = (int*)alloc((size_t)N * 4);
  int* offs = (int*)alloc((size_t)N * 4);
  float* nI = (float*)alloc((size_t)N * 4);
  float* nO = (float*)alloc((size_t)N * 4);
  unsigned short* hb0 = (unsigned short*)alloc((size_t)N * HID * 2);  // bf16 h
  unsigned short* hb1 = (unsigned short*)alloc((size_t)N * HID * 2);  // bf16 h

  hipMemsetAsync(ws, 0, zero_span, stream);

  // counting-sort CSR build: zero global atomics (LDS atomics only)
  k_hist<<<KB, 256, 0, stream>>>(src, dst, countsD, countsS, E, NB, KB);
  k_scanA<<<2 * NB, 256, 0, stream>>>(countsD, countsS, rows, NB, KB);
  k_scanB<<<2, 256, 0, stream>>>(rows, NB);
  k_scat<<<KB, 256, 0, stream>>>(src, dst, countsD, countsS, rows, bufD, bufS, E, NB, KB);
  k_csrB<<<2 * NB, 256, 0, stream>>>(bufD, bufS, countsD, countsS, rows, csr, deg,
                                     offs, nI, nO, E, N, NB, KB);

  // sort + embed + per-graph count in one dispatch
  int nblk = (N + 255) / 256;
  int nbS = nblk;
  int nbE = N / 16 + 1;
  k_fused<<<nbS + nbE + nblk, 256, 0, stream>>>(
      csr, offs, deg, node_feat, emb, nO, hb0, gid, cnt, N, nbS, nbE);

  int nblkG = (N + LIN_NODES - 1) / LIN_NODES;
  k_gl<false><<<nblkG, 256, 0, stream>>>(hb0, csr, offs, deg, nI, W[0], b[0],
                                         hb1, nullptr, nullptr, N, nO);
  k_gl<false><<<nblkG, 256, 0, stream>>>(hb1, csr, offs, deg, nI, W[1], b[1],
                                         hb0, nullptr, nullptr, N, nO);
  k_gl<true><<<nblkG, 256, 0, stream>>>(hb0, csr, offs, deg, nI, W[2], b[2],
                                        nullptr, gid, sums, N, nullptr);

  k_div<<<(NGRAPHS * HID + 255) / 256, 256, 0, stream>>>(sums, cnt, out);
}